// Round 6
// baseline (446.462 us; speedup 1.0000x reference)
//
#include <hip/hip_runtime.h>
#include <hip/hip_bf16.h>

typedef __bf16 bf16_t;
typedef __attribute__((ext_vector_type(8))) __bf16 bf16x8;
typedef __attribute__((ext_vector_type(4))) __bf16 bf16x4;
typedef __attribute__((ext_vector_type(4))) float floatx4;
typedef __attribute__((ext_vector_type(4))) int intx4;
typedef __attribute__((ext_vector_type(4))) unsigned uintx4;
typedef __attribute__((ext_vector_type(2))) unsigned uint2v;

#define NN 8192
#define FIN 256
#define FOUT 64
#define GAT_ALPHA 0.2f
#define JSPLIT 8
#define JSEG (NN / JSPLIT)          // 1024 j per wave
#define CHUNKJ 256                  // j per DMA chunk
#define NCHUNK (JSEG / CHUNKJ)      // 4
#define SUBSTRIDE 264               // 256B data + 8B pad (bank spread, 8B align)
#define WAVE_LDS (64 * SUBSTRIDE)   // 16,896 B per wave

// ---------------------------------------------------------------------------
// Kernel A: h = input @ W (fp32 in -> bf16 MFMA). Outputs:
//   hT [64][8192] bf16, E1/F1 fp32 [8192], ef2 packed (bf16 E2 | bf16 F2<<16).
// ---------------------------------------------------------------------------
__global__ __launch_bounds__(256) void gat_h_kernel(
    const float* __restrict__ input,    // [8192][256] fp32
    const float* __restrict__ W,        // [256][64] fp32
    const float* __restrict__ a,        // [128] fp32
    bf16_t* __restrict__ hT,            // [64][8192] bf16
    float* __restrict__ e1g, float* __restrict__ f1g,
    unsigned* __restrict__ ef2g)        // [8192] packed bf16 pair
{
    alignas(16) __shared__ bf16_t in_lds[32][264];
    alignas(16) __shared__ bf16_t wt_lds[64][264];
    __shared__ float h_lds[32][65];

    const int t  = threadIdx.x;
    const int i0 = blockIdx.x * 32;

    #pragma unroll
    for (int v = 0; v < 8; v++) {
        int u  = v * 256 + t;
        int i  = u >> 6;
        int k4 = (u & 63) * 4;
        floatx4 x = *(const floatx4*)(input + (size_t)(i0 + i) * FIN + k4);
        bf16x4 b;
        #pragma unroll
        for (int e = 0; e < 4; e++) b[e] = (bf16_t)x[e];
        *(bf16x4*)(&in_lds[i][k4]) = b;
    }
    #pragma unroll
    for (int v = 0; v < 16; v++) {
        int u  = v * 256 + t;
        int k  = u >> 4;
        int f4 = (u & 15) * 4;
        floatx4 wv = *(const floatx4*)(W + k * FOUT + f4);
        #pragma unroll
        for (int e = 0; e < 4; e++) wt_lds[f4 + e][k] = (bf16_t)wv[e];
    }
    __syncthreads();

    const int wave = t >> 6;
    const int lane = t & 63;
    const int i16  = (wave & 1) * 16;
    const int f32  = (wave >> 1) * 32;
    const int lm   = lane & 15;
    const int lq   = lane >> 4;

    floatx4 acc0 = {0.f, 0.f, 0.f, 0.f};
    floatx4 acc1 = {0.f, 0.f, 0.f, 0.f};
    #pragma unroll
    for (int ks = 0; ks < 8; ks++) {
        int ko = ks * 32 + lq * 8;
        bf16x8 af = *(const bf16x8*)(&in_lds[i16 + lm][ko]);
        bf16x8 b0 = *(const bf16x8*)(&wt_lds[f32 + lm][ko]);
        bf16x8 b1 = *(const bf16x8*)(&wt_lds[f32 + 16 + lm][ko]);
        acc0 = __builtin_amdgcn_mfma_f32_16x16x32_bf16(af, b0, acc0, 0, 0, 0);
        acc1 = __builtin_amdgcn_mfma_f32_16x16x32_bf16(af, b1, acc1, 0, 0, 0);
    }

    #pragma unroll
    for (int c = 0; c < 2; c++) {
        floatx4 acc = c ? acc1 : acc0;
        int f  = f32 + c * 16 + lm;
        int ib = i0 + i16 + lq * 4;
        bf16x4 hp;
        #pragma unroll
        for (int r = 0; r < 4; r++) hp[r] = (bf16_t)acc[r];
        *(bf16x4*)(hT + (size_t)f * NN + ib) = hp;
    }
    #pragma unroll
    for (int c = 0; c < 2; c++) {
        floatx4 acc = c ? acc1 : acc0;
        #pragma unroll
        for (int r = 0; r < 4; r++)
            h_lds[i16 + lq * 4 + r][f32 + c * 16 + lm] = acc[r];
    }
    __syncthreads();

    if (t < 64) {
        int r   = t & 31;
        int sel = t >> 5;
        const float* av = a + sel * FOUT;
        float s = 0.f;
        #pragma unroll 8
        for (int f = 0; f < FOUT; f++) s += h_lds[r][f] * av[f];
        int gi = i0 + r;
        float E = expf(s);
        float F = expf(GAT_ALPHA * s);
        if (sel == 0) {
            e1g[gi] = E; f1g[gi] = F;
        } else {
            unsigned eb = __builtin_bit_cast(unsigned short, (bf16_t)E);
            unsigned fb = __builtin_bit_cast(unsigned short, (bf16_t)F);
            ef2g[gi] = (fb << 16) | eb;
        }
    }
}

// ---------------------------------------------------------------------------
// Kernel B: barrier-free fused softmax+aggregation with global_load_lds DMA.
// 128 threads = 2 waves; each wave owns 16 rows x JSEG and a PRIVATE LDS
// buffer. Per chunk (16 rows x 256 j): 64 width-4 DMA instrs (256B contiguous
// per instr per row -> good DRAM streams, queue depth in DMA engine), then
// 8 MFMA steps reading adj from LDS (ds_read_b64, <=2-way bank conflicts).
// No __syncthreads anywhere -> no vmcnt(0) drains except one manual
// vmcnt(12) per chunk. hT/ef stay register-prefetched (L2-hot).
// ---------------------------------------------------------------------------
#define ISSUE_DMA(C)                                                           \
    {                                                                          \
        _Pragma("unroll")                                                      \
        for (int mm = 0; mm < 16; mm++) {                                      \
            const int* gsrc = adj + (size_t)(i0 + mm) * NN + jbase             \
                              + (C) * CHUNKJ + lane;                           \
            _Pragma("unroll")                                                  \
            for (int g = 0; g < 4; g++) {                                      \
                __builtin_amdgcn_global_load_lds(                              \
                    (const __attribute__((address_space(1))) unsigned*)        \
                        (gsrc + g * 64),                                       \
                    (__attribute__((address_space(3))) unsigned*)              \
                        (lbase + (g * 16 + mm) * SUBSTRIDE),                   \
                    4, 0, 0);                                                  \
            }                                                                  \
        }                                                                      \
    }

#define PREFETCH(P, JLOC)                                                      \
    {                                                                          \
        efb[P][0] = *(const uintx4*)(efp + (JLOC));                            \
        efb[P][1] = *(const uintx4*)(efp + (JLOC) + 4);                        \
        _Pragma("unroll")                                                      \
        for (int cc = 0; cc < 4; cc++)                                         \
            htb[P][cc] = *(const bf16x8*)(htp + (size_t)cc * 16 * NN + (JLOC));\
    }

__global__ __launch_bounds__(128, 2) void gat_att_kernel(
    const int* __restrict__ adj,        // [8192][8192] int32
    const bf16_t* __restrict__ hT,      // [64][8192] bf16
    const float* __restrict__ e1g, const float* __restrict__ f1g,
    const unsigned* __restrict__ ef2g,  // [8192] packed
    float* __restrict__ pacc,           // [JSPLIT][8192][64]
    float* __restrict__ prs)            // [JSPLIT][8192]
{
    __shared__ char alds[2][WAVE_LDS];  // 33,792 B -> 4 blocks/CU

    const int t     = threadIdx.x;
    const int wave  = t >> 6;
    const int lane  = t & 63;
    const int m     = lane & 15;        // A-frag row / C col
    const int q     = lane >> 4;        // quad: k = q*8+e
    const int i0    = blockIdx.x * 32 + wave * 16;
    const int js    = blockIdx.y;
    const int jbase = js * JSEG;
    const int row   = i0 + m;

    char* lbase = alds[wave];

    const float E1 = e1g[row];
    const float F1 = f1g[row];

    ISSUE_DMA(0);

    const unsigned* efp = ef2g + jbase + q * 8;
    const bf16_t*   htp = hT + (size_t)m * NN + jbase + q * 8;

    floatx4 acc[4];
    #pragma unroll
    for (int c = 0; c < 4; c++) acc[c] = (floatx4){0.f, 0.f, 0.f, 0.f};
    float rowsum = 0.f;

    bf16x8 htb[2][4];
    uintx4 efb[2][2];

    for (int c = 0; c < NCHUNK; c++) {
        const int jc = c * CHUNKJ;
        PREFETCH(0, jc);
        PREFETCH(1, jc + 32);
        // wait for this chunk's 64 DMA loads (12 newer reg loads may fly):
        // vmcnt(12) expcnt(7) lgkmcnt(15)
        __builtin_amdgcn_s_waitcnt(0x0F7C);

        #pragma unroll
        for (int s = 0; s < 8; s++) {
            const char* lsrc = lbase + (((s >> 1) * 16 + m) * SUBSTRIDE)
                               + ((s & 1) * 128) + (q * 32);
            uint2v a0 = *(const uint2v*)(lsrc);
            uint2v a1 = *(const uint2v*)(lsrc + 8);
            uint2v a2 = *(const uint2v*)(lsrc + 16);
            uint2v a3 = *(const uint2v*)(lsrc + 24);
            int adji[8];
            adji[0] = (int)a0.x; adji[1] = (int)a0.y;
            adji[2] = (int)a1.x; adji[3] = (int)a1.y;
            adji[4] = (int)a2.x; adji[5] = (int)a2.y;
            adji[6] = (int)a3.x; adji[7] = (int)a3.y;

            const int p = s & 1;
            bf16x8 wf;
            #pragma unroll
            for (int e = 0; e < 8; e++) {
                unsigned v = (e < 4) ? efb[p][0][e] : efb[p][1][e - 4];
                float e2 = __builtin_bit_cast(float, v << 16);
                float f2 = __builtin_bit_cast(float, v & 0xffff0000u);
                float pv = fmaxf(E1 * e2, F1 * f2);
                float wv = (adji[e] > 0) ? pv : 0.f;
                bf16_t wb = (bf16_t)wv;
                wf[e] = wb;
                rowsum += (float)wb;
            }
            bf16x8 hb0 = htb[p][0], hb1 = htb[p][1],
                   hb2 = htb[p][2], hb3 = htb[p][3];
            if (s < 6) PREFETCH(p, jc + (s + 2) * 32);
            acc[0] = __builtin_amdgcn_mfma_f32_16x16x32_bf16(wf, hb0, acc[0], 0, 0, 0);
            acc[1] = __builtin_amdgcn_mfma_f32_16x16x32_bf16(wf, hb1, acc[1], 0, 0, 0);
            acc[2] = __builtin_amdgcn_mfma_f32_16x16x32_bf16(wf, hb2, acc[2], 0, 0, 0);
            acc[3] = __builtin_amdgcn_mfma_f32_16x16x32_bf16(wf, hb3, acc[3], 0, 0, 0);
        }
        // all ds_reads of this chunk consumed above; pin order, then refill
        __builtin_amdgcn_sched_barrier(0);
        if (c + 1 < NCHUNK) ISSUE_DMA(c + 1);
    }

    // rowsum: reduce across the 4 quads holding row m
    rowsum += __shfl_xor(rowsum, 16, 64);
    rowsum += __shfl_xor(rowsum, 32, 64);
    if (lane < 16) prs[(size_t)js * NN + i0 + lane] = rowsum;

    // partial acc: C layout col=m (f), row=q*4+r
    float* pa = pacc + (size_t)js * NN * FOUT;
    #pragma unroll
    for (int c = 0; c < 4; c++) {
        #pragma unroll
        for (int r = 0; r < 4; r++)
            pa[(size_t)(i0 + q * 4 + r) * FOUT + c * 16 + m] = acc[c][r];
    }
}

// ---------------------------------------------------------------------------
// Kernel C: combine JSPLIT partials, normalize, ELU, store fp32.
// ---------------------------------------------------------------------------
__global__ __launch_bounds__(256) void gat_combine_kernel(
    const float* __restrict__ pacc,     // [JSPLIT][8192][64]
    const float* __restrict__ prs,      // [JSPLIT][8192]
    float* __restrict__ out)            // [8192][64]
{
    int idx = blockIdx.x * 256 + threadIdx.x;
    int i   = idx >> 4;
    floatx4 s = {0.f, 0.f, 0.f, 0.f};
    float rs  = 0.f;
    #pragma unroll
    for (int js = 0; js < JSPLIT; js++) {
        s  += *(const floatx4*)(pacc + (size_t)js * NN * FOUT + (size_t)idx * 4);
        rs += prs[(size_t)js * NN + i];
    }
    float rinv = (rs > 0.f) ? 1.0f / rs : 0.f;
    floatx4 r;
    #pragma unroll
    for (int e = 0; e < 4; e++) {
        float x = s[e] * rinv;
        r[e] = (x > 0.f) ? x : (expf(x) - 1.0f);
    }
    *(floatx4*)(out + (size_t)idx * 4) = r;
}

// ---------------------------------------------------------------------------
extern "C" void kernel_launch(void* const* d_in, const int* in_sizes, int n_in,
                              void* d_out, int out_size, void* d_ws, size_t ws_size,
                              hipStream_t stream) {
    const float* input = (const float*)d_in[0];     // [8192][256] fp32
    const int*   adj   = (const int*)d_in[1];       // [8192][8192] int32
    const float* W     = (const float*)d_in[2];     // [256][64] fp32
    const float* a     = (const float*)d_in[3];     // [128] fp32
    float*       out   = (float*)d_out;             // [8192][64] fp32

    char* ws = (char*)d_ws;
    bf16_t*   hT   = (bf16_t*)ws;                   // 1 MiB
    float*    e1g  = (float*)(ws + (1 << 20));
    float*    f1g  = e1g + NN;
    unsigned* ef2g = (unsigned*)(f1g + NN);
    float*    pacc = (float*)(ef2g + NN);           // 16 MiB
    float*    prs  = pacc + (size_t)JSPLIT * NN * FOUT;

    gat_h_kernel<<<NN / 32, 256, 0, stream>>>(input, W, a, hT, e1g, f1g, ef2g);

    dim3 gridB(NN / 32, JSPLIT);
    gat_att_kernel<<<gridB, 128, 0, stream>>>(adj, hT, e1g, f1g, ef2g,
                                              pacc, prs);

    gat_combine_kernel<<<NN * FOUT / 4 / 256, 256, 0, stream>>>(pacc, prs, out);
}

// Round 7
// 400.439 us; speedup vs baseline: 1.1149x; 1.1149x over previous
//
#include <hip/hip_runtime.h>
#include <hip/hip_bf16.h>

typedef __bf16 bf16_t;
typedef __attribute__((ext_vector_type(8))) __bf16 bf16x8;
typedef __attribute__((ext_vector_type(4))) __bf16 bf16x4;
typedef __attribute__((ext_vector_type(4))) float floatx4;
typedef __attribute__((ext_vector_type(4))) int intx4;
typedef __attribute__((ext_vector_type(4))) unsigned uintx4;

#define NN 8192
#define FIN 256
#define FOUT 64
#define GAT_ALPHA 0.2f
#define JSPLIT 4
#define JSEG (NN / JSPLIT)          // 2048 j per wave
#define PHASEJ 256                  // j per pipeline phase (1 KB per row)
#define NPHASE (JSEG / PHASEJ)      // 8
#define ADJ_STRIDE 260              // ints per LDS row: 16B-aligned, 2-way-only

// ---------------------------------------------------------------------------
// Kernel A: h = input @ W (fp32 in -> bf16 MFMA). Outputs:
//   hT [64][8192] bf16, E1/F1 fp32 [8192], ef2 packed (bf16 E2 | bf16 F2<<16).
// ---------------------------------------------------------------------------
__global__ __launch_bounds__(256) void gat_h_kernel(
    const float* __restrict__ input,    // [8192][256] fp32
    const float* __restrict__ W,        // [256][64] fp32
    const float* __restrict__ a,        // [128] fp32
    bf16_t* __restrict__ hT,            // [64][8192] bf16
    float* __restrict__ e1g, float* __restrict__ f1g,
    unsigned* __restrict__ ef2g)        // [8192] packed bf16 pair
{
    alignas(16) __shared__ bf16_t in_lds[32][264];
    alignas(16) __shared__ bf16_t wt_lds[64][264];
    __shared__ float h_lds[32][65];

    const int t  = threadIdx.x;
    const int i0 = blockIdx.x * 32;

    #pragma unroll
    for (int v = 0; v < 8; v++) {
        int u  = v * 256 + t;
        int i  = u >> 6;
        int k4 = (u & 63) * 4;
        floatx4 x = *(const floatx4*)(input + (size_t)(i0 + i) * FIN + k4);
        bf16x4 b;
        #pragma unroll
        for (int e = 0; e < 4; e++) b[e] = (bf16_t)x[e];
        *(bf16x4*)(&in_lds[i][k4]) = b;
    }
    #pragma unroll
    for (int v = 0; v < 16; v++) {
        int u  = v * 256 + t;
        int k  = u >> 4;
        int f4 = (u & 15) * 4;
        floatx4 wv = *(const floatx4*)(W + k * FOUT + f4);
        #pragma unroll
        for (int e = 0; e < 4; e++) wt_lds[f4 + e][k] = (bf16_t)wv[e];
    }
    __syncthreads();

    const int wave = t >> 6;
    const int lane = t & 63;
    const int i16  = (wave & 1) * 16;
    const int f32  = (wave >> 1) * 32;
    const int lm   = lane & 15;
    const int lq   = lane >> 4;

    floatx4 acc0 = {0.f, 0.f, 0.f, 0.f};
    floatx4 acc1 = {0.f, 0.f, 0.f, 0.f};
    #pragma unroll
    for (int ks = 0; ks < 8; ks++) {
        int ko = ks * 32 + lq * 8;
        bf16x8 af = *(const bf16x8*)(&in_lds[i16 + lm][ko]);
        bf16x8 b0 = *(const bf16x8*)(&wt_lds[f32 + lm][ko]);
        bf16x8 b1 = *(const bf16x8*)(&wt_lds[f32 + 16 + lm][ko]);
        acc0 = __builtin_amdgcn_mfma_f32_16x16x32_bf16(af, b0, acc0, 0, 0, 0);
        acc1 = __builtin_amdgcn_mfma_f32_16x16x32_bf16(af, b1, acc1, 0, 0, 0);
    }

    #pragma unroll
    for (int c = 0; c < 2; c++) {
        floatx4 acc = c ? acc1 : acc0;
        int f  = f32 + c * 16 + lm;
        int ib = i0 + i16 + lq * 4;
        bf16x4 hp;
        #pragma unroll
        for (int r = 0; r < 4; r++) hp[r] = (bf16_t)acc[r];
        *(bf16x4*)(hT + (size_t)f * NN + ib) = hp;
    }
    #pragma unroll
    for (int c = 0; c < 2; c++) {
        floatx4 acc = c ? acc1 : acc0;
        #pragma unroll
        for (int r = 0; r < 4; r++)
            h_lds[i16 + lq * 4 + r][f32 + c * 16 + lm] = acc[r];
    }
    __syncthreads();

    if (t < 64) {
        int r   = t & 31;
        int sel = t >> 5;
        const float* av = a + sel * FOUT;
        float s = 0.f;
        #pragma unroll 8
        for (int f = 0; f < FOUT; f++) s += h_lds[r][f] * av[f];
        int gi = i0 + r;
        float E = expf(s);
        float F = expf(GAT_ALPHA * s);
        if (sel == 0) {
            e1g[gi] = E; f1g[gi] = F;
        } else {
            unsigned eb = __builtin_bit_cast(unsigned short, (bf16_t)E);
            unsigned fb = __builtin_bit_cast(unsigned short, (bf16_t)F);
            ef2g[gi] = (fb << 16) | eb;
        }
    }
}

// ---------------------------------------------------------------------------
// Kernel B: barrier-free fused softmax+aggregation, wave-private LDS transpose.
// Each wave: 16 rows x JSEG. Per phase (256 j): 16 global dwordx4 loads
// (each a 1 KB SINGLE-STREAM burst from one adj row -> DRAM-friendly),
// issued one full phase ahead; ds_write into the wave's private LDS
// quadrant; per K-step ds_read_b128 x2 gives each lane its A-frag adj ints.
// w = adj>0 ? max(E1*E2, F1*F2) : 0. No __syncthreads anywhere -> the
// compiler emits fine-grained vmcnt/lgkmcnt; cross-wave overlap intact.
// ---------------------------------------------------------------------------
__global__ __launch_bounds__(128, 2) void gat_att_kernel(
    const int* __restrict__ adj,        // [8192][8192] int32
    const bf16_t* __restrict__ hT,      // [64][8192] bf16
    const float* __restrict__ e1g, const float* __restrict__ f1g,
    const unsigned* __restrict__ ef2g,  // [8192] packed
    float* __restrict__ pacc,           // [JSPLIT][8192][64]
    float* __restrict__ prs)            // [JSPLIT][8192]
{
    __shared__ int alds[2][16 * ADJ_STRIDE];    // 33,280 B -> 4 blocks/CU

    const int t    = threadIdx.x;
    const int wave = t >> 6;
    const int lane = t & 63;
    const int m    = lane & 15;         // A-frag row / C col
    const int q    = lane >> 4;         // quad: k = q*8+e
    const int i0   = blockIdx.x * 32 + wave * 16;
    const int js   = blockIdx.y;
    const int jb   = js * JSEG;
    const int row  = i0 + m;

    int* lds = alds[wave];

    const float E1 = e1g[row];
    const float F1 = f1g[row];

    floatx4 acc[4];
    #pragma unroll
    for (int c = 0; c < 4; c++) acc[c] = (floatx4){0.f, 0.f, 0.f, 0.f};
    float rowsum = 0.f;

    // phase-0 global loads: one 1KB burst per row
    intx4 g[16];
    #pragma unroll
    for (int r = 0; r < 16; r++)
        g[r] = *(const intx4*)(adj + (size_t)(i0 + r) * NN + jb + 4 * lane);

    for (int p = 0; p < NPHASE; p++) {
        // prior phase's ds_reads fully retired (results already consumed)
        __builtin_amdgcn_s_waitcnt(0xC07F);     // vmcnt(63) exp(7) lgkm(0)

        #pragma unroll
        for (int r = 0; r < 16; r++)
            *(intx4*)(lds + r * ADJ_STRIDE + 4 * lane) = g[r];

        if (p + 1 < NPHASE) {
            #pragma unroll
            for (int r = 0; r < 16; r++)
                g[r] = *(const intx4*)(adj + (size_t)(i0 + r) * NN + jb
                                       + (p + 1) * PHASEJ + 4 * lane);
        }

        const unsigned* efp = ef2g + jb + p * PHASEJ + q * 8;
        const bf16_t*   htp = hT + (size_t)m * NN + jb + p * PHASEJ + q * 8;
        const int*      ap  = lds + m * ADJ_STRIDE + q * 8;

        // K-step software pipeline: prefetch ef2/hT one step ahead
        uintx4 e0 = *(const uintx4*)(efp);
        uintx4 e1 = *(const uintx4*)(efp + 4);
        bf16x8 hb[4];
        #pragma unroll
        for (int c = 0; c < 4; c++)
            hb[c] = *(const bf16x8*)(htp + (size_t)c * 16 * NN);

        #pragma unroll
        for (int ks = 0; ks < 8; ks++) {
            intx4 a0 = *(const intx4*)(ap + ks * 32);
            intx4 a1 = *(const intx4*)(ap + ks * 32 + 4);

            uintx4 ce0 = e0, ce1 = e1;
            bf16x8 chb0 = hb[0], chb1 = hb[1], chb2 = hb[2], chb3 = hb[3];
            if (ks < 7) {
                e0 = *(const uintx4*)(efp + (ks + 1) * 32);
                e1 = *(const uintx4*)(efp + (ks + 1) * 32 + 4);
                #pragma unroll
                for (int c = 0; c < 4; c++)
                    hb[c] = *(const bf16x8*)(htp + (size_t)c * 16 * NN
                                             + (ks + 1) * 32);
            }

            bf16x8 wf;
            #pragma unroll
            for (int e = 0; e < 8; e++) {
                int av     = (e < 4) ? a0[e] : a1[e - 4];
                unsigned v = (e < 4) ? ce0[e] : ce1[e - 4];
                float e2 = __builtin_bit_cast(float, v << 16);
                float f2 = __builtin_bit_cast(float, v & 0xffff0000u);
                float pv = fmaxf(E1 * e2, F1 * f2);
                float wv = (av > 0) ? pv : 0.f;
                bf16_t wb = (bf16_t)wv;
                wf[e] = wb;
                rowsum += (float)wb;
            }
            acc[0] = __builtin_amdgcn_mfma_f32_16x16x32_bf16(wf, chb0, acc[0], 0, 0, 0);
            acc[1] = __builtin_amdgcn_mfma_f32_16x16x32_bf16(wf, chb1, acc[1], 0, 0, 0);
            acc[2] = __builtin_amdgcn_mfma_f32_16x16x32_bf16(wf, chb2, acc[2], 0, 0, 0);
            acc[3] = __builtin_amdgcn_mfma_f32_16x16x32_bf16(wf, chb3, acc[3], 0, 0, 0);
        }
    }

    // rowsum: reduce across the 4 quads holding row m
    rowsum += __shfl_xor(rowsum, 16, 64);
    rowsum += __shfl_xor(rowsum, 32, 64);
    if (lane < 16) prs[(size_t)js * NN + i0 + lane] = rowsum;

    // partial acc: C layout col=m (f), row=q*4+r
    float* pa = pacc + (size_t)js * NN * FOUT;
    #pragma unroll
    for (int c = 0; c < 4; c++) {
        #pragma unroll
        for (int r = 0; r < 4; r++)
            pa[(size_t)(i0 + q * 4 + r) * FOUT + c * 16 + m] = acc[c][r];
    }
}

// ---------------------------------------------------------------------------
// Kernel C: combine JSPLIT partials, normalize, ELU, store fp32.
// ---------------------------------------------------------------------------
__global__ __launch_bounds__(256) void gat_combine_kernel(
    const float* __restrict__ pacc,     // [JSPLIT][8192][64]
    const float* __restrict__ prs,      // [JSPLIT][8192]
    float* __restrict__ out)            // [8192][64]
{
    int idx = blockIdx.x * 256 + threadIdx.x;
    int i   = idx >> 4;
    floatx4 s = {0.f, 0.f, 0.f, 0.f};
    float rs  = 0.f;
    #pragma unroll
    for (int js = 0; js < JSPLIT; js++) {
        s  += *(const floatx4*)(pacc + (size_t)js * NN * FOUT + (size_t)idx * 4);
        rs += prs[(size_t)js * NN + i];
    }
    float rinv = (rs > 0.f) ? 1.0f / rs : 0.f;
    floatx4 r;
    #pragma unroll
    for (int e = 0; e < 4; e++) {
        float x = s[e] * rinv;
        r[e] = (x > 0.f) ? x : (expf(x) - 1.0f);
    }
    *(floatx4*)(out + (size_t)idx * 4) = r;
}

// ---------------------------------------------------------------------------
extern "C" void kernel_launch(void* const* d_in, const int* in_sizes, int n_in,
                              void* d_out, int out_size, void* d_ws, size_t ws_size,
                              hipStream_t stream) {
    const float* input = (const float*)d_in[0];     // [8192][256] fp32
    const int*   adj   = (const int*)d_in[1];       // [8192][8192] int32
    const float* W     = (const float*)d_in[2];     // [256][64] fp32
    const float* a     = (const float*)d_in[3];     // [128] fp32
    float*       out   = (float*)d_out;             // [8192][64] fp32

    char* ws = (char*)d_ws;
    bf16_t*   hT   = (bf16_t*)ws;                   // 1 MiB
    float*    e1g  = (float*)(ws + (1 << 20));
    float*    f1g  = e1g + NN;
    unsigned* ef2g = (unsigned*)(f1g + NN);
    float*    pacc = (float*)(ef2g + NN);           // JSPLIT*8192*64*4 = 8 MiB
    float*    prs  = pacc + (size_t)JSPLIT * NN * FOUT;

    gat_h_kernel<<<NN / 32, 256, 0, stream>>>(input, W, a, hT, e1g, f1g, ef2g);

    dim3 gridB(NN / 32, JSPLIT);
    gat_att_kernel<<<gridB, 128, 0, stream>>>(adj, hT, e1g, f1g, ef2g,
                                              pacc, prs);

    gat_combine_kernel<<<NN * FOUT / 4 / 256, 256, 0, stream>>>(pacc, prs, out);
}